// Round 2
// baseline (391.069 us; speedup 1.0000x reference)
//
#include <hip/hip_runtime.h>
#include <math.h>

// GraphAttention single-node aggregate, restructured:
//   w = kernel @ attn_neigh            (128)   -- prep kernel
//   x_t = x @ kernel                   (64)    -- prep kernel
//   s_i = X_i . w ; online softmax over N; acc = sum p_i * X_i (128)  -- main
//   out = 0.75 * ((acc/L) @ kernel) + 0.25 * x_t                      -- finalize
// attn_self drops out entirely (softmax shift invariance).

#define TPB 512          // 8 waves per block in main kernel
#define MAXBLK 512       // partial-buffer blocks
#define PART_STRIDE 136  // floats per block partial: [0]=m,[1]=l,[8..135]=acc
#define PART_BASE 256    // float offset in ws where partials start (0..127=w, 128..191=x_t)

__global__ __launch_bounds__(128) void gat_prep(
    const float* __restrict__ x, const float* __restrict__ kern,
    const float* __restrict__ attn_neigh, float* __restrict__ ws) {
  int t = threadIdx.x;  // 128 threads
  // w[t] = sum_c kernel[t][c] * attn_neigh[c]
  float s = 0.f;
#pragma unroll 8
  for (int c = 0; c < 64; ++c) s += kern[t * 64 + c] * attn_neigh[c];
  ws[t] = s;
  if (t < 64) {
    // x_t[t] = sum_j x[j] * kernel[j][t]
    float s2 = 0.f;
#pragma unroll 8
    for (int j = 0; j < 128; ++j) s2 += x[j] * kern[j * 64 + t];
    ws[128 + t] = s2;
  }
}

__global__ __launch_bounds__(TPB) void gat_main(
    const float4* __restrict__ X4, const float* __restrict__ ws,
    float* __restrict__ part, int N, int npairs, int totalWaves) {
  const int lane = threadIdx.x & 63;
  const int half = lane >> 5;       // 0: even row, 1: odd row of the pair
  const int hl = lane & 31;
  const int wid = threadIdx.x >> 6; // wave in block (0..7)
  const int gwave = blockIdx.x * (TPB / 64) + wid;

  const float4 wv = ((const float4*)ws)[hl];  // w fragment: features 4*hl..4*hl+3

  float m = -INFINITY, l = 0.f;
  float ax = 0.f, ay = 0.f, az = 0.f, aw = 0.f;

  for (int p = gwave; p < npairs; p += totalWaves) {
    const bool ok = (2 * p + half) < N;  // uniform within each 32-lane half
    float4 xv = make_float4(0.f, 0.f, 0.f, 0.f);
    if (ok) xv = X4[(size_t)p * 64 + lane];
    float s = xv.x * wv.x + xv.y * wv.y + xv.z * wv.z + xv.w * wv.w;
    // reduce across the 32-lane half (xor offsets < 32 stay within the half)
    s += __shfl_xor(s, 1);
    s += __shfl_xor(s, 2);
    s += __shfl_xor(s, 4);
    s += __shfl_xor(s, 8);
    s += __shfl_xor(s, 16);
    const float mn = ok ? fmaxf(m, s) : m;
    const float corr = (m == mn) ? 1.f : __expf(m - mn);  // safe for m=-inf
    const float pw = ok ? __expf(s - mn) : 0.f;
    l = l * corr + pw;
    ax = ax * corr + pw * xv.x;
    ay = ay * corr + pw * xv.y;
    az = az * corr + pw * xv.z;
    aw = aw * corr + pw * xv.w;
    m = mn;
  }

  // combine the two 32-lane halves of this wave
  const float m_o = __shfl_xor(m, 32);
  const float l_o = __shfl_xor(l, 32);
  const float axo = __shfl_xor(ax, 32);
  const float ayo = __shfl_xor(ay, 32);
  const float azo = __shfl_xor(az, 32);
  const float awo = __shfl_xor(aw, 32);
  const float M2 = fmaxf(m, m_o);
  const float c0 = (m == -INFINITY) ? 0.f : __expf(m - M2);
  const float c1 = (m_o == -INFINITY) ? 0.f : __expf(m_o - M2);
  const float l2 = l * c0 + l_o * c1;
  const float bx = ax * c0 + axo * c1;
  const float by = ay * c0 + ayo * c1;
  const float bz = az * c0 + azo * c1;
  const float bw = aw * c0 + awo * c1;

  __shared__ float sm[TPB / 64];
  __shared__ float sl[TPB / 64];
  __shared__ float sacc[TPB / 64][128];
  if (lane < 32) {
    sacc[wid][hl * 4 + 0] = bx;
    sacc[wid][hl * 4 + 1] = by;
    sacc[wid][hl * 4 + 2] = bz;
    sacc[wid][hl * 4 + 3] = bw;
    if (hl == 0) { sm[wid] = M2; sl[wid] = l2; }
  }
  __syncthreads();

  // first 32 threads combine the block's 8 wave-partials, write block partial
  if (threadIdx.x < 32) {
    float Mb = -INFINITY;
#pragma unroll
    for (int w2 = 0; w2 < TPB / 64; ++w2) Mb = fmaxf(Mb, sm[w2]);
    float Lb = 0.f, fx = 0.f, fy = 0.f, fz = 0.f, fw = 0.f;
#pragma unroll
    for (int w2 = 0; w2 < TPB / 64; ++w2) {
      const float sc = (sm[w2] == -INFINITY) ? 0.f : __expf(sm[w2] - Mb);
      Lb += sc * sl[w2];
      fx += sc * sacc[w2][hl * 4 + 0];
      fy += sc * sacc[w2][hl * 4 + 1];
      fz += sc * sacc[w2][hl * 4 + 2];
      fw += sc * sacc[w2][hl * 4 + 3];
    }
    float* pb = part + (size_t)blockIdx.x * PART_STRIDE;
    if (hl == 0) { pb[0] = Mb; pb[1] = Lb; }
    float4 v = make_float4(fx, fy, fz, fw);
    ((float4*)(pb + 8))[hl] = v;  // 16B-aligned: PART_BASE/STRIDE multiples of 8
  }
}

__global__ __launch_bounds__(256) void gat_fin(
    const float* __restrict__ kern, const float* __restrict__ ws,
    float* __restrict__ out, int nblk) {
  __shared__ float scale[MAXBLK];
  __shared__ float red[256];
  __shared__ float feats[128];
  const int t = threadIdx.x;  // 256 threads
  const float* part = ws + PART_BASE;

  // global max M over block partials
  float m = -INFINITY;
  for (int b = t; b < nblk; b += 256) m = fmaxf(m, part[(size_t)b * PART_STRIDE]);
  red[t] = m;
  __syncthreads();
  for (int s = 128; s > 0; s >>= 1) {
    if (t < s) red[t] = fmaxf(red[t], red[t + s]);
    __syncthreads();
  }
  const float M = red[0];
  __syncthreads();

  // scales + global L
  float lp = 0.f;
  for (int b = t; b < nblk; b += 256) {
    const float mb = part[(size_t)b * PART_STRIDE];
    const float sc = (mb == -INFINITY) ? 0.f : __expf(mb - M);
    scale[b] = sc;
    lp += sc * part[(size_t)b * PART_STRIDE + 1];
  }
  red[t] = lp;
  __syncthreads();
  for (int s = 128; s > 0; s >>= 1) {
    if (t < s) red[t] += red[t + s];
    __syncthreads();
  }
  const float L = red[0];
  __syncthreads();

  // feats[j] = (1/L) * sum_b scale_b * acc_b[j]   (this is attn @ X, 128-dim)
  if (t < 128) {
    float f = 0.f;
    for (int b = 0; b < nblk; ++b) f += scale[b] * part[(size_t)b * PART_STRIDE + 8 + t];
    feats[t] = f / L;
  }
  __syncthreads();

  // out[c] = 0.75 * (feats @ kernel)[c] + 0.25 * x_t[c]
  if (t < 64) {
    float s = 0.f;
#pragma unroll 8
    for (int j = 0; j < 128; ++j) s += feats[j] * kern[j * 64 + t];
    out[t] = 0.75f * s + 0.25f * ws[128 + t];
  }
}

extern "C" void kernel_launch(void* const* d_in, const int* in_sizes, int n_in,
                              void* d_out, int out_size, void* d_ws, size_t ws_size,
                              hipStream_t stream) {
  const float* x          = (const float*)d_in[0];
  const float* X          = (const float*)d_in[1];
  const float* kern       = (const float*)d_in[2];
  // d_in[3] = attn_self: unused — softmax is invariant to the constant shift.
  const float* attn_neigh = (const float*)d_in[4];
  float* ws  = (float*)d_ws;
  float* out = (float*)d_out;

  const int N = in_sizes[1] / 128;
  const int npairs = (N + 1) >> 1;

  // Guard: ensure the prep region (PART_BASE floats) and at least one block
  // partial fit in ws. With any sane ws_size this leaves nblk == MAXBLK.
  int nblk = MAXBLK;
  const size_t availF = ws_size / 4;
  if (availF < (size_t)PART_BASE + (size_t)MAXBLK * PART_STRIDE) {
    long cap = ((long)availF - PART_BASE) / PART_STRIDE;
    nblk = (cap < 1) ? 1 : (int)cap;
  }
  const int totalWaves = nblk * (TPB / 64);

  gat_prep<<<1, 128, 0, stream>>>(x, kern, attn_neigh, ws);
  gat_main<<<nblk, TPB, 0, stream>>>((const float4*)X, ws, ws + PART_BASE,
                                     N, npairs, totalWaves);
  gat_fin<<<1, 256, 0, stream>>>(kern, ws, out, nblk);
}